// Round 4
// baseline (539.680 us; speedup 1.0000x reference)
//
#include <hip/hip_runtime.h>
#include <hip/hip_bf16.h>

// ---------------------------------------------------------------------------
// GCN forward: out = A_hat @ ( (relu(A_hat @ (X@W1))) @ W2 )
// A_hat = D^-1/2 (A) D^-1/2, edges given as (row, col) pairs incl. self loops.
//
// R2: internal tensors bf16, GEMMs on MFMA 16x16x32_bf16, SpMM gathers bf16.
// R3: csr_w eliminated — w_e = dinv[r]*dinv[c] is separable. GEMM epilogues
//     pre-scale their output rows by dinv (the SpMM column factor); SpMMs
//     apply dinv[r] once per row. fill_csr is now a single 4B scatter/edge
//     (was 2 arrays -> 160 MB of sector writebacks, 116 us).
// ---------------------------------------------------------------------------

typedef __attribute__((ext_vector_type(8))) short short8;
typedef __attribute__((ext_vector_type(4))) float floatx4;

static __device__ __forceinline__ ushort f32_to_bf16_bits(float f) {
    union { ushort u; __hip_bfloat16 b; } cv;
    cv.b = __float2bfloat16(f);
    return cv.u;
}
static __device__ __forceinline__ float bf16lo_to_f32(uint u) {
    return __uint_as_float(u << 16);
}
static __device__ __forceinline__ float bf16hi_to_f32(uint u) {
    return __uint_as_float(u & 0xffff0000u);
}

// ---------------- graph prep --------------------------------------------

__global__ void count_deg_kernel(const int* __restrict__ rows, int* __restrict__ deg, int E) {
    int i = blockIdx.x * blockDim.x + threadIdx.x;
    if (i < E) atomicAdd(&deg[rows[i]], 1);
}

__global__ void dinv_kernel(const int* __restrict__ deg, float* __restrict__ dinv, int n) {
    int i = blockIdx.x * blockDim.x + threadIdx.x;
    if (i < n) {
        float d = (float)deg[i];
        dinv[i] = 1.0f / sqrtf(fmaxf(d, 1e-24f));
    }
}

__global__ __launch_bounds__(256) void scan_phase1_kernel(
    const int* __restrict__ deg, int* __restrict__ row_ptr,
    int* __restrict__ block_total, int n) {
    __shared__ int tsum[256];
    int t = threadIdx.x;
    int base = blockIdx.x * 1024 + t * 4;
    int v0 = (base + 0 < n) ? deg[base + 0] : 0;
    int v1 = (base + 1 < n) ? deg[base + 1] : 0;
    int v2 = (base + 2 < n) ? deg[base + 2] : 0;
    int v3 = (base + 3 < n) ? deg[base + 3] : 0;
    tsum[t] = v0 + v1 + v2 + v3;
    __syncthreads();
    for (int off = 1; off < 256; off <<= 1) {
        int x = (t >= off) ? tsum[t - off] : 0;
        __syncthreads();
        tsum[t] += x;
        __syncthreads();
    }
    if (t == 255) block_total[blockIdx.x] = tsum[255];
    int run = (t == 0) ? 0 : tsum[t - 1];
    if (base + 0 < n) row_ptr[base + 0] = run; run += v0;
    if (base + 1 < n) row_ptr[base + 1] = run; run += v1;
    if (base + 2 < n) row_ptr[base + 2] = run; run += v2;
    if (base + 3 < n) row_ptr[base + 3] = run;
}

__global__ __launch_bounds__(256) void scan_phase2_kernel(
    const int* __restrict__ block_total, int* __restrict__ block_offset, int G) {
    __shared__ int s[256];
    int t = threadIdx.x;
    s[t] = (t < G) ? block_total[t] : 0;
    __syncthreads();
    for (int off = 1; off < 256; off <<= 1) {
        int x = (t >= off) ? s[t - off] : 0;
        __syncthreads();
        s[t] += x;
        __syncthreads();
    }
    if (t < G) block_offset[t] = (t == 0) ? 0 : s[t - 1];
    if (t == 0) block_offset[G] = s[255];
}

__global__ __launch_bounds__(256) void scan_phase3_kernel(
    int* __restrict__ row_ptr, int* __restrict__ cnt,
    const int* __restrict__ block_offset, int n, int G) {
    int i = blockIdx.x * blockDim.x + threadIdx.x;
    if (i < n) {
        int v = row_ptr[i] + block_offset[i >> 10];
        row_ptr[i] = v;
        cnt[i] = v;
    }
    if (i == 0) row_ptr[n] = block_offset[G];
}

// R3: single 4B scatter per edge (col only — weights are folded elsewhere).
__global__ void fill_csr_kernel(const int* __restrict__ rows, const int* __restrict__ colsIn,
                                int* __restrict__ cnt, int* __restrict__ csr_col, int E) {
    int i = blockIdx.x * blockDim.x + threadIdx.x;
    if (i >= E) return;
    int r = rows[i];
    int c = colsIn[i];
    int pos = atomicAdd(&cnt[r], 1);
    csr_col[pos] = c;
}

// ---------------- weight cast + transpose --------------------------------
// out[n][k] = bf16(in[k][n]);  in is [K][Ncols] fp32 row-major.
__global__ void cast_transpose_kernel(const float* __restrict__ in, ushort* __restrict__ out,
                                      int K, int Ncols) {
    int i = blockIdx.x * blockDim.x + threadIdx.x;  // i = n*K + k
    if (i >= K * Ncols) return;
    int n = i / K, k = i % K;
    out[i] = f32_to_bf16_bits(in[(size_t)k * Ncols + n]);
}

// ---------------- MFMA GEMM ----------------------------------------------
// C[M,NCOLS](bf16) = dinv[row] * (A[M,KTOT] @ Bt^T); Bt is [NCOLS][KTOT] bf16.
// A fp32 (converted in-register) if AF32, else bf16.
// Block: 256 thr = 4 waves; tile 64 rows x NCOLS cols; wave w -> rows 16w..16w+15.
// MFMA layouts (HW-verified per guide m89/m120):
//   a_frag lane l: A[m=l&15][k=(l>>4)*8+j]
//   b_frag lane l: B[k=(l>>4)*8+j][n=l&15]
//   d      lane l: D[row=(l>>4)*4+r][col=l&15]
template <int KTOT, int NCOLS, bool AF32>
__global__ __launch_bounds__(256) void gemm_mfma_kernel(
    const void* __restrict__ Aptr, const ushort* __restrict__ Bt,
    const float* __restrict__ dinv, ushort* __restrict__ Cbf, int M) {
    constexpr int KP = 128;           // K panel in LDS
    constexpr int COLT = NCOLS / 16;  // 8 (gemm1) or 4 (gemm2)
    __shared__ ushort Bs[NCOLS][KP + 8];
    int tid = threadIdx.x;
    int wave = tid >> 6, lane = tid & 63;
    int quad = lane >> 4, l16 = lane & 15;
    int row0 = blockIdx.x * 64;
    int rowA = row0 + wave * 16 + l16;
    int rowAc = min(rowA, M - 1);

    floatx4 acc[COLT];
#pragma unroll
    for (int t = 0; t < COLT; t++) acc[t] = (floatx4){0.f, 0.f, 0.f, 0.f};

    for (int kp = 0; kp < KTOT; kp += KP) {
        // stage B panel: Bs[n][k] = Bt[n][kp+k], coalesced 16B units
        for (int u = tid; u < NCOLS * (KP / 8); u += 256) {
            int n = u / (KP / 8);
            int k8 = (u % (KP / 8)) * 8;
            *(short8*)&Bs[n][k8] = *(const short8*)(Bt + (size_t)n * KTOT + kp + k8);
        }
        __syncthreads();
#pragma unroll
        for (int kc = 0; kc < KP / 32; kc++) {
            int kk = kp + kc * 32 + quad * 8;
            short8 a;
            if (AF32) {
                const float* ap = (const float*)Aptr + (size_t)rowAc * KTOT + kk;
#pragma unroll
                for (int j = 0; j < 8; j++) a[j] = (short)f32_to_bf16_bits(ap[j]);
            } else {
                a = *(const short8*)((const ushort*)Aptr + (size_t)rowAc * KTOT + kk);
            }
#pragma unroll
            for (int t = 0; t < COLT; t++) {
                short8 b = *(const short8*)&Bs[t * 16 + l16][kc * 32 + quad * 8];
                acc[t] = __builtin_amdgcn_mfma_f32_16x16x32_bf16(a, b, acc[t], 0, 0, 0);
            }
        }
        __syncthreads();
    }

#pragma unroll
    for (int r = 0; r < 4; r++) {
        int row = row0 + wave * 16 + quad * 4 + r;
        if (row < M) {
            float dv = dinv[row];
#pragma unroll
            for (int t = 0; t < COLT; t++)
                Cbf[(size_t)row * NCOLS + t * 16 + l16] = f32_to_bf16_bits(dv * acc[t][r]);
        }
    }
}

// ---------------- SpMM (bf16 gather, fp32 accumulate) ---------------------
// Xin rows are pre-scaled by dinv[col]; apply dinv[row] once at the end.
// F=128: wave per row, lane holds 2 features (one dword gather per edge).
__global__ __launch_bounds__(256) void spmm_bf16_f128_kernel(
    const int* __restrict__ row_ptr, const int* __restrict__ cols,
    const float* __restrict__ dinv, const ushort* __restrict__ Xin,
    ushort* __restrict__ Yout, int n) {
    int wv = (int)((blockIdx.x * 256 + threadIdx.x) >> 6);
    int lane = threadIdx.x & 63;
    if (wv >= n) return;
    int beg = row_ptr[wv], end = row_ptr[wv + 1];
    float a0 = 0.f, a1 = 0.f;
    int e = beg;
    for (; e + 4 <= end; e += 4) {
        int c0 = cols[e], c1 = cols[e + 1], c2 = cols[e + 2], c3 = cols[e + 3];
        uint u0 = *(const uint*)(Xin + (size_t)c0 * 128 + lane * 2);
        uint u1 = *(const uint*)(Xin + (size_t)c1 * 128 + lane * 2);
        uint u2 = *(const uint*)(Xin + (size_t)c2 * 128 + lane * 2);
        uint u3 = *(const uint*)(Xin + (size_t)c3 * 128 + lane * 2);
        a0 += bf16lo_to_f32(u0); a1 += bf16hi_to_f32(u0);
        a0 += bf16lo_to_f32(u1); a1 += bf16hi_to_f32(u1);
        a0 += bf16lo_to_f32(u2); a1 += bf16hi_to_f32(u2);
        a0 += bf16lo_to_f32(u3); a1 += bf16hi_to_f32(u3);
    }
    for (; e < end; e++) {
        uint u = *(const uint*)(Xin + (size_t)cols[e] * 128 + lane * 2);
        a0 += bf16lo_to_f32(u);
        a1 += bf16hi_to_f32(u);
    }
    float dv = dinv[wv];
    a0 = fmaxf(dv * a0, 0.f);  // relu (layer 1 only uses this kernel)
    a1 = fmaxf(dv * a1, 0.f);
    uint out = (uint)f32_to_bf16_bits(a0) | ((uint)f32_to_bf16_bits(a1) << 16);
    *(uint*)(Yout + (size_t)wv * 128 + lane * 2) = out;
}

// F=64: wave per row, lane holds 1 feature (ushort gather), fp32 output.
__global__ __launch_bounds__(256) void spmm_bf16_f64_kernel(
    const int* __restrict__ row_ptr, const int* __restrict__ cols,
    const float* __restrict__ dinv, const ushort* __restrict__ Xin,
    float* __restrict__ Yout, int n) {
    int wv = (int)((blockIdx.x * 256 + threadIdx.x) >> 6);
    int lane = threadIdx.x & 63;
    if (wv >= n) return;
    int beg = row_ptr[wv], end = row_ptr[wv + 1];
    float acc = 0.f;
    int e = beg;
    for (; e + 4 <= end; e += 4) {
        int c0 = cols[e], c1 = cols[e + 1], c2 = cols[e + 2], c3 = cols[e + 3];
        uint u0 = Xin[(size_t)c0 * 64 + lane];
        uint u1 = Xin[(size_t)c1 * 64 + lane];
        uint u2 = Xin[(size_t)c2 * 64 + lane];
        uint u3 = Xin[(size_t)c3 * 64 + lane];
        acc += bf16lo_to_f32(u0);
        acc += bf16lo_to_f32(u1);
        acc += bf16lo_to_f32(u2);
        acc += bf16lo_to_f32(u3);
    }
    for (; e < end; e++) {
        acc += bf16lo_to_f32((uint)Xin[(size_t)cols[e] * 64 + lane]);
    }
    Yout[(size_t)wv * 64 + lane] = dinv[wv] * acc;
}

// ---------------- launch ---------------------------------------------------

extern "C" void kernel_launch(void* const* d_in, const int* in_sizes, int n_in,
                              void* d_out, int out_size, void* d_ws, size_t ws_size,
                              hipStream_t stream) {
    const float* X  = (const float*)d_in[0];
    const float* W1 = (const float*)d_in[1];
    const float* W2 = (const float*)d_in[2];
    const int* erow = (const int*)d_in[3];
    const int* ecol = (const int*)d_in[4];

    const int N = in_sizes[0] / 256;  // 100000
    const int E = in_sizes[3];        // 1700000
    const int G = (N + 1023) >> 10;   // scan blocks (98 <= 256)

    char* ws = (char*)d_ws;
    size_t off = 0;
    auto carve = [&](size_t bytes) -> char* {
        char* p = ws + off;
        off += (bytes + 255) & ~(size_t)255;
        return p;
    };
    int*    deg       = (int*)   carve((size_t)N * 4);
    float*  dinv      = (float*) carve((size_t)N * 4);
    int*    row_ptr   = (int*)   carve((size_t)(N + 1) * 4);
    int*    cnt       = (int*)   carve((size_t)N * 4);
    int*    blk_total = (int*)   carve((size_t)G * 4);
    int*    blk_off   = (int*)   carve((size_t)(G + 1) * 4);
    int*    csr_col   = (int*)   carve((size_t)E * 4);
    ushort* W1t       = (ushort*)carve((size_t)256 * 128 * 2);  // [128][256]
    ushort* W2t       = (ushort*)carve((size_t)128 * 64 * 2);   // [64][128]
    ushort* XW1       = (ushort*)carve((size_t)N * 128 * 2);
    ushort* H         = (ushort*)carve((size_t)N * 128 * 2);
    ushort* HW2       = (ushort*)carve((size_t)N * 64 * 2);

    // graph normalization + CSR build
    hipMemsetAsync(deg, 0, (size_t)N * 4, stream);
    count_deg_kernel<<<(E + 255) / 256, 256, 0, stream>>>(erow, deg, E);
    dinv_kernel<<<(N + 255) / 256, 256, 0, stream>>>(deg, dinv, N);
    scan_phase1_kernel<<<G, 256, 0, stream>>>(deg, row_ptr, blk_total, N);
    scan_phase2_kernel<<<1, 256, 0, stream>>>(blk_total, blk_off, G);
    scan_phase3_kernel<<<(N + 255) / 256, 256, 0, stream>>>(row_ptr, cnt, blk_off, N, G);
    fill_csr_kernel<<<(E + 255) / 256, 256, 0, stream>>>(erow, ecol, cnt, csr_col, E);

    // weights: cast + transpose to bf16 [n][k]
    cast_transpose_kernel<<<(256 * 128 + 255) / 256, 256, 0, stream>>>(W1, W1t, 256, 128);
    cast_transpose_kernel<<<(128 * 64 + 255) / 256, 256, 0, stream>>>(W2, W2t, 128, 64);

    // GEMM1: XW1(bf16) = dinv .* (X @ W1)   (pre-scaled for SpMM1 gather)
    gemm_mfma_kernel<256, 128, true><<<(N + 63) / 64, 256, 0, stream>>>(
        (const void*)X, W1t, dinv, XW1, N);

    // SpMM1: H(bf16) = relu(dinv .* sum gather XW1)
    spmm_bf16_f128_kernel<<<(N + 3) / 4, 256, 0, stream>>>(row_ptr, csr_col, dinv, XW1, H, N);

    // GEMM2: HW2(bf16) = dinv .* (H @ W2)   (pre-scaled for SpMM2 gather)
    gemm_mfma_kernel<128, 64, false><<<(N + 63) / 64, 256, 0, stream>>>(
        (const void*)H, W2t, dinv, HW2, N);

    // SpMM2: out(fp32) = dinv .* sum gather HW2
    spmm_bf16_f64_kernel<<<(N + 3) / 4, 256, 0, stream>>>(row_ptr, csr_col, dinv, HW2, (float*)d_out, N);
}

// Round 5
// 462.303 us; speedup vs baseline: 1.1674x; 1.1674x over previous
//
#include <hip/hip_runtime.h>
#include <hip/hip_bf16.h>

// ---------------------------------------------------------------------------
// GCN forward: out = A_hat @ ( (relu(A_hat @ (X@W1))) @ W2 )
// A_hat = D^-1/2 (A) D^-1/2, edges given as (row, col) pairs incl. self loops.
//
// R2: internal tensors bf16, GEMMs on MFMA 16x16x32_bf16, SpMM gathers bf16.
// R3: csr_w eliminated (w separable) — GEMM epilogues pre-scale rows by dinv,
//     SpMMs apply dinv[row] once.
// R4: fill_csr (136us: latency-bound random 4B scatter + global atomics,
//     108MB sector writebacks) replaced by 2-level counting sort:
//     histA (LDS hist by row>>9) -> scanB -> binC (coalesced bucket-major
//     packed writes) -> scatterD (per-bucket block, LDS row cursors, scatter
//     confined to ~35KB L2-resident window). All atomics in LDS.
// ---------------------------------------------------------------------------

typedef __attribute__((ext_vector_type(8))) short short8;
typedef __attribute__((ext_vector_type(4))) float floatx4;

static __device__ __forceinline__ ushort f32_to_bf16_bits(float f) {
    union { ushort u; __hip_bfloat16 b; } cv;
    cv.b = __float2bfloat16(f);
    return cv.u;
}
static __device__ __forceinline__ float bf16lo_to_f32(uint u) {
    return __uint_as_float(u << 16);
}
static __device__ __forceinline__ float bf16hi_to_f32(uint u) {
    return __uint_as_float(u & 0xffff0000u);
}

// ---------------- graph prep --------------------------------------------

__global__ void count_deg_kernel(const int* __restrict__ rows, int* __restrict__ deg, int E) {
    int i = blockIdx.x * blockDim.x + threadIdx.x;
    if (i < E) atomicAdd(&deg[rows[i]], 1);
}

__global__ void dinv_kernel(const int* __restrict__ deg, float* __restrict__ dinv, int n) {
    int i = blockIdx.x * blockDim.x + threadIdx.x;
    if (i < n) {
        float d = (float)deg[i];
        dinv[i] = 1.0f / sqrtf(fmaxf(d, 1e-24f));
    }
}

// ---- generic 3-phase device-wide exclusive scan (1024 elems per block) ----
__global__ __launch_bounds__(256) void scan_phase1_kernel(
    const int* __restrict__ deg, int* __restrict__ row_ptr,
    int* __restrict__ block_total, int n) {
    __shared__ int tsum[256];
    int t = threadIdx.x;
    int base = blockIdx.x * 1024 + t * 4;
    int v0 = (base + 0 < n) ? deg[base + 0] : 0;
    int v1 = (base + 1 < n) ? deg[base + 1] : 0;
    int v2 = (base + 2 < n) ? deg[base + 2] : 0;
    int v3 = (base + 3 < n) ? deg[base + 3] : 0;
    tsum[t] = v0 + v1 + v2 + v3;
    __syncthreads();
    for (int off = 1; off < 256; off <<= 1) {
        int x = (t >= off) ? tsum[t - off] : 0;
        __syncthreads();
        tsum[t] += x;
        __syncthreads();
    }
    if (t == 255) block_total[blockIdx.x] = tsum[255];
    int run = (t == 0) ? 0 : tsum[t - 1];
    if (base + 0 < n) row_ptr[base + 0] = run; run += v0;
    if (base + 1 < n) row_ptr[base + 1] = run; run += v1;
    if (base + 2 < n) row_ptr[base + 2] = run; run += v2;
    if (base + 3 < n) row_ptr[base + 3] = run;
}

__global__ __launch_bounds__(256) void scan_phase2_kernel(
    const int* __restrict__ block_total, int* __restrict__ block_offset, int G) {
    __shared__ int s[256];
    int t = threadIdx.x;
    s[t] = (t < G) ? block_total[t] : 0;
    __syncthreads();
    for (int off = 1; off < 256; off <<= 1) {
        int x = (t >= off) ? s[t - off] : 0;
        __syncthreads();
        s[t] += x;
        __syncthreads();
    }
    if (t < G) block_offset[t] = (t == 0) ? 0 : s[t - 1];
    if (t == 0) block_offset[G] = s[255];
}

__global__ __launch_bounds__(256) void scan_phase3_kernel(
    int* __restrict__ row_ptr, const int* __restrict__ block_offset, int n, int G) {
    int i = blockIdx.x * blockDim.x + threadIdx.x;
    if (i < n) row_ptr[i] += block_offset[i >> 10];
    if (i == 0) row_ptr[n] = block_offset[G];
}

// ---- R4 CSR build: two-level counting sort ------------------------------
// Buckets: row>>9 (512 rows each, <=256 buckets for N<131072).
// EPB edges per block.
#define CSR_EPB 8192

// Pass A: per-(bucket,block) histogram, bucket-major layout.
__global__ __launch_bounds__(256) void edge_hist_kernel(
    const int* __restrict__ rows, int* __restrict__ histG, int E, int nblk) {
    __shared__ int h[256];
    int t = threadIdx.x;
    h[t] = 0;
    __syncthreads();
    int base = blockIdx.x * CSR_EPB;
    int end = min(base + CSR_EPB, E);
    for (int i = base + t; i < end; i += 256)
        atomicAdd(&h[rows[i] >> 9], 1);
    __syncthreads();
    histG[t * nblk + blockIdx.x] = h[t];
}

// Pass C: bin edges bucket-major; packed (row&511)<<17 | col  (N < 2^17).
__global__ __launch_bounds__(256) void edge_bin_kernel(
    const int* __restrict__ rows, const int* __restrict__ colsIn,
    const int* __restrict__ offG, int* __restrict__ binP, int E, int nblk) {
    __shared__ int cur[256];
    int t = threadIdx.x;
    cur[t] = offG[t * nblk + blockIdx.x];
    __syncthreads();
    int base = blockIdx.x * CSR_EPB;
    int end = min(base + CSR_EPB, E);
    for (int i = base + t; i < end; i += 256) {
        int r = rows[i], c = colsIn[i];
        int p = atomicAdd(&cur[r >> 9], 1);
        binP[p] = ((r & 511) << 17) | c;
    }
}

// Pass D: one block per bucket; LDS row cursors from row_ptr; final scatter
// confined to this bucket's csr_col window.
__global__ __launch_bounds__(256) void edge_scatter_kernel(
    const int* __restrict__ binP, const int* __restrict__ offG,
    const int* __restrict__ row_ptr, int* __restrict__ csr_col,
    int E, int nblk, int N) {
    __shared__ int cur[512];
    int b = blockIdx.x;
    int rbase = b << 9;
    if (rbase >= N) return;
    int t = threadIdx.x;
    for (int i = t; i < 512; i += 256) {
        int r = rbase + i;
        cur[i] = (r < N) ? row_ptr[r] : 0;
    }
    __syncthreads();
    int bs = offG[b * nblk];
    int be = (b + 1 < 256) ? offG[(b + 1) * nblk] : E;
    for (int e = bs + t; e < be; e += 256) {
        int pk = binP[e];
        int rl = pk >> 17;
        int c = pk & 0x1ffff;
        int p = atomicAdd(&cur[rl], 1);
        csr_col[p] = c;
    }
}

// ---------------- weight cast + transpose --------------------------------
// out[n][k] = bf16(in[k][n]);  in is [K][Ncols] fp32 row-major.
__global__ void cast_transpose_kernel(const float* __restrict__ in, ushort* __restrict__ out,
                                      int K, int Ncols) {
    int i = blockIdx.x * blockDim.x + threadIdx.x;  // i = n*K + k
    if (i >= K * Ncols) return;
    int n = i / K, k = i % K;
    out[i] = f32_to_bf16_bits(in[(size_t)k * Ncols + n]);
}

// ---------------- MFMA GEMM ----------------------------------------------
// C[M,NCOLS](bf16) = dinv[row] * (A[M,KTOT] @ Bt^T); Bt is [NCOLS][KTOT] bf16.
// A fp32 (converted in-register) if AF32, else bf16.
// MFMA layouts (HW-verified per guide m89/m120):
//   a_frag lane l: A[m=l&15][k=(l>>4)*8+j]
//   b_frag lane l: B[k=(l>>4)*8+j][n=l&15]
//   d      lane l: D[row=(l>>4)*4+r][col=l&15]
template <int KTOT, int NCOLS, bool AF32>
__global__ __launch_bounds__(256) void gemm_mfma_kernel(
    const void* __restrict__ Aptr, const ushort* __restrict__ Bt,
    const float* __restrict__ dinv, ushort* __restrict__ Cbf, int M) {
    constexpr int KP = 128;           // K panel in LDS
    constexpr int COLT = NCOLS / 16;  // 8 (gemm1) or 4 (gemm2)
    __shared__ ushort Bs[NCOLS][KP + 8];
    int tid = threadIdx.x;
    int wave = tid >> 6, lane = tid & 63;
    int quad = lane >> 4, l16 = lane & 15;
    int row0 = blockIdx.x * 64;
    int rowA = row0 + wave * 16 + l16;
    int rowAc = min(rowA, M - 1);

    floatx4 acc[COLT];
#pragma unroll
    for (int t = 0; t < COLT; t++) acc[t] = (floatx4){0.f, 0.f, 0.f, 0.f};

    for (int kp = 0; kp < KTOT; kp += KP) {
        for (int u = tid; u < NCOLS * (KP / 8); u += 256) {
            int n = u / (KP / 8);
            int k8 = (u % (KP / 8)) * 8;
            *(short8*)&Bs[n][k8] = *(const short8*)(Bt + (size_t)n * KTOT + kp + k8);
        }
        __syncthreads();
#pragma unroll
        for (int kc = 0; kc < KP / 32; kc++) {
            int kk = kp + kc * 32 + quad * 8;
            short8 a;
            if (AF32) {
                const float* ap = (const float*)Aptr + (size_t)rowAc * KTOT + kk;
#pragma unroll
                for (int j = 0; j < 8; j++) a[j] = (short)f32_to_bf16_bits(ap[j]);
            } else {
                a = *(const short8*)((const ushort*)Aptr + (size_t)rowAc * KTOT + kk);
            }
#pragma unroll
            for (int t = 0; t < COLT; t++) {
                short8 b = *(const short8*)&Bs[t * 16 + l16][kc * 32 + quad * 8];
                acc[t] = __builtin_amdgcn_mfma_f32_16x16x32_bf16(a, b, acc[t], 0, 0, 0);
            }
        }
        __syncthreads();
    }

#pragma unroll
    for (int r = 0; r < 4; r++) {
        int row = row0 + wave * 16 + quad * 4 + r;
        if (row < M) {
            float dv = dinv[row];
#pragma unroll
            for (int t = 0; t < COLT; t++)
                Cbf[(size_t)row * NCOLS + t * 16 + l16] = f32_to_bf16_bits(dv * acc[t][r]);
        }
    }
}

// ---------------- SpMM (bf16 gather, fp32 accumulate) ---------------------
// Xin rows are pre-scaled by dinv[col]; apply dinv[row] once at the end.
__global__ __launch_bounds__(256) void spmm_bf16_f128_kernel(
    const int* __restrict__ row_ptr, const int* __restrict__ cols,
    const float* __restrict__ dinv, const ushort* __restrict__ Xin,
    ushort* __restrict__ Yout, int n) {
    int wv = (int)((blockIdx.x * 256 + threadIdx.x) >> 6);
    int lane = threadIdx.x & 63;
    if (wv >= n) return;
    int beg = row_ptr[wv], end = row_ptr[wv + 1];
    float a0 = 0.f, a1 = 0.f;
    int e = beg;
    for (; e + 4 <= end; e += 4) {
        int c0 = cols[e], c1 = cols[e + 1], c2 = cols[e + 2], c3 = cols[e + 3];
        uint u0 = *(const uint*)(Xin + (size_t)c0 * 128 + lane * 2);
        uint u1 = *(const uint*)(Xin + (size_t)c1 * 128 + lane * 2);
        uint u2 = *(const uint*)(Xin + (size_t)c2 * 128 + lane * 2);
        uint u3 = *(const uint*)(Xin + (size_t)c3 * 128 + lane * 2);
        a0 += bf16lo_to_f32(u0); a1 += bf16hi_to_f32(u0);
        a0 += bf16lo_to_f32(u1); a1 += bf16hi_to_f32(u1);
        a0 += bf16lo_to_f32(u2); a1 += bf16hi_to_f32(u2);
        a0 += bf16lo_to_f32(u3); a1 += bf16hi_to_f32(u3);
    }
    for (; e < end; e++) {
        uint u = *(const uint*)(Xin + (size_t)cols[e] * 128 + lane * 2);
        a0 += bf16lo_to_f32(u);
        a1 += bf16hi_to_f32(u);
    }
    float dv = dinv[wv];
    a0 = fmaxf(dv * a0, 0.f);  // relu
    a1 = fmaxf(dv * a1, 0.f);
    uint out = (uint)f32_to_bf16_bits(a0) | ((uint)f32_to_bf16_bits(a1) << 16);
    *(uint*)(Yout + (size_t)wv * 128 + lane * 2) = out;
}

__global__ __launch_bounds__(256) void spmm_bf16_f64_kernel(
    const int* __restrict__ row_ptr, const int* __restrict__ cols,
    const float* __restrict__ dinv, const ushort* __restrict__ Xin,
    float* __restrict__ Yout, int n) {
    int wv = (int)((blockIdx.x * 256 + threadIdx.x) >> 6);
    int lane = threadIdx.x & 63;
    if (wv >= n) return;
    int beg = row_ptr[wv], end = row_ptr[wv + 1];
    float acc = 0.f;
    int e = beg;
    for (; e + 4 <= end; e += 4) {
        int c0 = cols[e], c1 = cols[e + 1], c2 = cols[e + 2], c3 = cols[e + 3];
        uint u0 = Xin[(size_t)c0 * 64 + lane];
        uint u1 = Xin[(size_t)c1 * 64 + lane];
        uint u2 = Xin[(size_t)c2 * 64 + lane];
        uint u3 = Xin[(size_t)c3 * 64 + lane];
        acc += bf16lo_to_f32(u0);
        acc += bf16lo_to_f32(u1);
        acc += bf16lo_to_f32(u2);
        acc += bf16lo_to_f32(u3);
    }
    for (; e < end; e++) {
        acc += bf16lo_to_f32((uint)Xin[(size_t)cols[e] * 64 + lane]);
    }
    Yout[(size_t)wv * 64 + lane] = dinv[wv] * acc;
}

// ---------------- launch ---------------------------------------------------

extern "C" void kernel_launch(void* const* d_in, const int* in_sizes, int n_in,
                              void* d_out, int out_size, void* d_ws, size_t ws_size,
                              hipStream_t stream) {
    const float* X  = (const float*)d_in[0];
    const float* W1 = (const float*)d_in[1];
    const float* W2 = (const float*)d_in[2];
    const int* erow = (const int*)d_in[3];
    const int* ecol = (const int*)d_in[4];

    const int N = in_sizes[0] / 256;  // 100000 (< 2^17 required for binP packing)
    const int E = in_sizes[3];        // 1700000
    const int G = (N + 1023) >> 10;   // row scan blocks (98 <= 256)

    const int nblk = (E + CSR_EPB - 1) / CSR_EPB;  // 208
    const int SL = 256 * nblk;                     // hist scan length
    const int GS = (SL + 1023) >> 10;              // 52 <= 256

    char* ws = (char*)d_ws;
    size_t off = 0;
    auto carve = [&](size_t bytes) -> char* {
        char* p = ws + off;
        off += (bytes + 255) & ~(size_t)255;
        return p;
    };
    int*    deg       = (int*)   carve((size_t)N * 4);
    float*  dinv      = (float*) carve((size_t)N * 4);
    int*    row_ptr   = (int*)   carve((size_t)(N + 1) * 4);
    int*    blk_total = (int*)   carve((size_t)(G > GS ? G : GS) * 4);
    int*    blk_off   = (int*)   carve((size_t)((G > GS ? G : GS) + 1) * 4);
    int*    offG      = (int*)   carve((size_t)(SL + 1) * 4);
    int*    binP      = (int*)   carve((size_t)E * 4);
    int*    csr_col   = (int*)   carve((size_t)E * 4);
    ushort* W1t       = (ushort*)carve((size_t)256 * 128 * 2);  // [128][256]
    ushort* W2t       = (ushort*)carve((size_t)128 * 64 * 2);   // [64][128]
    ushort* XW1       = (ushort*)carve((size_t)N * 128 * 2);
    ushort* H         = (ushort*)carve((size_t)N * 128 * 2);
    ushort* HW2       = (ushort*)carve((size_t)N * 64 * 2);

    // degrees + dinv + row_ptr
    hipMemsetAsync(deg, 0, (size_t)N * 4, stream);
    count_deg_kernel<<<(E + 255) / 256, 256, 0, stream>>>(erow, deg, E);
    dinv_kernel<<<(N + 255) / 256, 256, 0, stream>>>(deg, dinv, N);
    scan_phase1_kernel<<<G, 256, 0, stream>>>(deg, row_ptr, blk_total, N);
    scan_phase2_kernel<<<1, 256, 0, stream>>>(blk_total, blk_off, G);
    scan_phase3_kernel<<<(N + 255) / 256, 256, 0, stream>>>(row_ptr, blk_off, N, G);

    // CSR build: 2-level counting sort (R4)
    edge_hist_kernel<<<nblk, 256, 0, stream>>>(erow, offG, E, nblk);
    scan_phase1_kernel<<<GS, 256, 0, stream>>>(offG, offG, blk_total, SL);  // in-place ok: phase1 reads then writes same elems
    scan_phase2_kernel<<<1, 256, 0, stream>>>(blk_total, blk_off, GS);
    scan_phase3_kernel<<<(SL + 255) / 256, 256, 0, stream>>>(offG, blk_off, SL, GS);
    edge_bin_kernel<<<nblk, 256, 0, stream>>>(erow, ecol, offG, binP, E, nblk);
    edge_scatter_kernel<<<256, 256, 0, stream>>>(binP, offG, row_ptr, csr_col, E, nblk, N);

    // weights: cast + transpose to bf16 [n][k]
    cast_transpose_kernel<<<(256 * 128 + 255) / 256, 256, 0, stream>>>(W1, W1t, 256, 128);
    cast_transpose_kernel<<<(128 * 64 + 255) / 256, 256, 0, stream>>>(W2, W2t, 128, 64);

    // GEMM1: XW1(bf16) = dinv .* (X @ W1)
    gemm_mfma_kernel<256, 128, true><<<(N + 63) / 64, 256, 0, stream>>>(
        (const void*)X, W1t, dinv, XW1, N);

    // SpMM1: H(bf16) = relu(dinv .* sum gather XW1)
    spmm_bf16_f128_kernel<<<(N + 3) / 4, 256, 0, stream>>>(row_ptr, csr_col, dinv, XW1, H, N);

    // GEMM2: HW2(bf16) = dinv .* (H @ W2)
    gemm_mfma_kernel<128, 64, false><<<(N + 63) / 64, 256, 0, stream>>>(
        (const void*)H, W2t, dinv, HW2, N);

    // SpMM2: out(fp32) = dinv .* sum gather HW2
    spmm_bf16_f64_kernel<<<(N + 3) / 4, 256, 0, stream>>>(row_ptr, csr_col, dinv, HW2, (float*)d_out, N);
}

// Round 6
// 440.767 us; speedup vs baseline: 1.2244x; 1.0489x over previous
//
#include <hip/hip_runtime.h>
#include <hip/hip_bf16.h>

// ---------------------------------------------------------------------------
// GCN forward: out = A_hat @ ( (relu(A_hat @ (X@W1))) @ W2 )
// A_hat = D^-1/2 (A) D^-1/2, edges given as (row, col) pairs incl. self loops.
//
// R2: internal tensors bf16, GEMMs on MFMA 16x16x32_bf16, SpMM gathers bf16.
// R3: csr_w eliminated (w separable) — GEMM epilogues pre-scale rows by dinv.
// R4: CSR build via 2-level counting sort (all atomics in LDS).
// R5: (a) preliminary counting sort of edges by col>>9 so each row's CSR list
//     ends up approximately column-sorted -> concurrent SpMM waves sweep the
//     gather table in sync -> L2-resident window (was FETCH 190MB vs 32MB
//     ideal on SpMM1). (b) count_deg's 1.7M random global atomics replaced by
//     per-bucket LDS histogram over binP (deg_from_bin).
// ---------------------------------------------------------------------------

typedef __attribute__((ext_vector_type(8))) short short8;
typedef __attribute__((ext_vector_type(4))) float floatx4;

static __device__ __forceinline__ ushort f32_to_bf16_bits(float f) {
    union { ushort u; __hip_bfloat16 b; } cv;
    cv.b = __float2bfloat16(f);
    return cv.u;
}
static __device__ __forceinline__ float bf16lo_to_f32(uint u) {
    return __uint_as_float(u << 16);
}
static __device__ __forceinline__ float bf16hi_to_f32(uint u) {
    return __uint_as_float(u & 0xffff0000u);
}

#define CSR_EPB 8192

// ---------------- graph prep ----------------------------------------------

__global__ void dinv_kernel(const int* __restrict__ deg, float* __restrict__ dinv, int n) {
    int i = blockIdx.x * blockDim.x + threadIdx.x;
    if (i < n) {
        float d = (float)deg[i];
        dinv[i] = 1.0f / sqrtf(fmaxf(d, 1e-24f));
    }
}

// ---- generic 3-phase device-wide exclusive scan (1024 elems per block) ----
__global__ __launch_bounds__(256) void scan_phase1_kernel(
    const int* __restrict__ in, int* __restrict__ out,
    int* __restrict__ block_total, int n) {
    __shared__ int tsum[256];
    int t = threadIdx.x;
    int base = blockIdx.x * 1024 + t * 4;
    int v0 = (base + 0 < n) ? in[base + 0] : 0;
    int v1 = (base + 1 < n) ? in[base + 1] : 0;
    int v2 = (base + 2 < n) ? in[base + 2] : 0;
    int v3 = (base + 3 < n) ? in[base + 3] : 0;
    tsum[t] = v0 + v1 + v2 + v3;
    __syncthreads();
    for (int off = 1; off < 256; off <<= 1) {
        int x = (t >= off) ? tsum[t - off] : 0;
        __syncthreads();
        tsum[t] += x;
        __syncthreads();
    }
    if (t == 255) block_total[blockIdx.x] = tsum[255];
    int run = (t == 0) ? 0 : tsum[t - 1];
    if (base + 0 < n) out[base + 0] = run; run += v0;
    if (base + 1 < n) out[base + 1] = run; run += v1;
    if (base + 2 < n) out[base + 2] = run; run += v2;
    if (base + 3 < n) out[base + 3] = run;
}

__global__ __launch_bounds__(256) void scan_phase2_kernel(
    const int* __restrict__ block_total, int* __restrict__ block_offset, int G) {
    __shared__ int s[256];
    int t = threadIdx.x;
    s[t] = (t < G) ? block_total[t] : 0;
    __syncthreads();
    for (int off = 1; off < 256; off <<= 1) {
        int x = (t >= off) ? s[t - off] : 0;
        __syncthreads();
        s[t] += x;
        __syncthreads();
    }
    if (t < G) block_offset[t] = (t == 0) ? 0 : s[t - 1];
    if (t == 0) block_offset[G] = s[255];
}

__global__ __launch_bounds__(256) void scan_phase3_kernel(
    int* __restrict__ arr, const int* __restrict__ block_offset, int n, int G) {
    int i = blockIdx.x * blockDim.x + threadIdx.x;
    if (i < n) arr[i] += block_offset[i >> 10];
    if (i == 0) arr[n] = block_offset[G];
}

// ---- R5 CSR build: col-sort then row-sort counting sorts ------------------
// All bucket keys are key>>9 (<=196 buckets for N=100k; LDS arrays use 256).

// hist of key>>9 from a plain int array, bucket-major output.
__global__ __launch_bounds__(256) void edge_hist_kernel(
    const int* __restrict__ keys, int* __restrict__ histG, int E, int nblk) {
    __shared__ int h[256];
    int t = threadIdx.x;
    h[t] = 0;
    __syncthreads();
    int base = blockIdx.x * CSR_EPB;
    int end = min(base + CSR_EPB, E);
    for (int i = base + t; i < end; i += 256)
        atomicAdd(&h[keys[i] >> 9], 1);
    __syncthreads();
    histG[t * nblk + blockIdx.x] = h[t];
}

// hist of e2[i].x>>9 (row key) from the pair array.
__global__ __launch_bounds__(256) void edge_hist2_kernel(
    const int2* __restrict__ e2, int* __restrict__ histG, int E, int nblk) {
    __shared__ int h[256];
    int t = threadIdx.x;
    h[t] = 0;
    __syncthreads();
    int base = blockIdx.x * CSR_EPB;
    int end = min(base + CSR_EPB, E);
    for (int i = base + t; i < end; i += 256)
        atomicAdd(&h[e2[i].x >> 9], 1);
    __syncthreads();
    histG[t * nblk + blockIdx.x] = h[t];
}

// bin edges by col bucket -> (row,col) pair array, bucket-major.
__global__ __launch_bounds__(256) void col_bin_kernel(
    const int* __restrict__ rows, const int* __restrict__ colsIn,
    const int* __restrict__ offG, int2* __restrict__ e2, int E, int nblk) {
    __shared__ int cur[256];
    int t = threadIdx.x;
    cur[t] = offG[t * nblk + blockIdx.x];
    __syncthreads();
    int base = blockIdx.x * CSR_EPB;
    int end = min(base + CSR_EPB, E);
    for (int i = base + t; i < end; i += 256) {
        int r = rows[i], c = colsIn[i];
        int p = atomicAdd(&cur[c >> 9], 1);
        e2[p] = make_int2(r, c);
    }
}

// bin col-sorted pairs by row bucket -> packed (row&511)<<17 | col (N < 2^17).
__global__ __launch_bounds__(256) void row_bin_kernel(
    const int2* __restrict__ e2, const int* __restrict__ offG,
    int* __restrict__ binP, int E, int nblk) {
    __shared__ int cur[256];
    int t = threadIdx.x;
    cur[t] = offG[t * nblk + blockIdx.x];
    __syncthreads();
    int base = blockIdx.x * CSR_EPB;
    int end = min(base + CSR_EPB, E);
    for (int i = base + t; i < end; i += 256) {
        int2 rc = e2[i];
        int p = atomicAdd(&cur[rc.x >> 9], 1);
        binP[p] = ((rc.x & 511) << 17) | rc.y;
    }
}

// per-row degrees via per-bucket LDS histogram over binP (no global atomics).
__global__ __launch_bounds__(256) void deg_from_bin_kernel(
    const int* __restrict__ binP, const int* __restrict__ offG1,
    int* __restrict__ deg, int E, int nblk, int N) {
    __shared__ int cnt[512];
    int b = blockIdx.x;
    int rbase = b << 9;
    if (rbase >= N) return;
    int t = threadIdx.x;
    for (int i = t; i < 512; i += 256) cnt[i] = 0;
    __syncthreads();
    int bs = offG1[b * nblk];
    int be = (b + 1 < 256) ? offG1[(b + 1) * nblk] : E;
    for (int e = bs + t; e < be; e += 256)
        atomicAdd(&cnt[binP[e] >> 17], 1);
    __syncthreads();
    for (int i = t; i < 512; i += 256) {
        int r = rbase + i;
        if (r < N) deg[r] = cnt[i];
    }
}

// one block per row bucket; LDS row cursors; scatter confined to this
// bucket's csr_col window (preserves col-sorted-ish order within rows).
__global__ __launch_bounds__(256) void edge_scatter_kernel(
    const int* __restrict__ binP, const int* __restrict__ offG,
    const int* __restrict__ row_ptr, int* __restrict__ csr_col,
    int E, int nblk, int N) {
    __shared__ int cur[512];
    int b = blockIdx.x;
    int rbase = b << 9;
    if (rbase >= N) return;
    int t = threadIdx.x;
    for (int i = t; i < 512; i += 256) {
        int r = rbase + i;
        cur[i] = (r < N) ? row_ptr[r] : 0;
    }
    __syncthreads();
    int bs = offG[b * nblk];
    int be = (b + 1 < 256) ? offG[(b + 1) * nblk] : E;
    for (int e = bs + t; e < be; e += 256) {
        int pk = binP[e];
        int rl = pk >> 17;
        int c = pk & 0x1ffff;
        int p = atomicAdd(&cur[rl], 1);
        csr_col[p] = c;
    }
}

// ---------------- weight cast + transpose ---------------------------------
// out[n][k] = bf16(in[k][n]);  in is [K][Ncols] fp32 row-major.
__global__ void cast_transpose_kernel(const float* __restrict__ in, ushort* __restrict__ out,
                                      int K, int Ncols) {
    int i = blockIdx.x * blockDim.x + threadIdx.x;  // i = n*K + k
    if (i >= K * Ncols) return;
    int n = i / K, k = i % K;
    out[i] = f32_to_bf16_bits(in[(size_t)k * Ncols + n]);
}

// ---------------- MFMA GEMM -----------------------------------------------
// C[M,NCOLS](bf16) = dinv[row] * (A[M,KTOT] @ Bt^T); Bt is [NCOLS][KTOT] bf16.
// A fp32 (converted in-register) if AF32, else bf16.
// MFMA layouts (HW-verified per guide m89/m120):
//   a_frag lane l: A[m=l&15][k=(l>>4)*8+j]
//   b_frag lane l: B[k=(l>>4)*8+j][n=l&15]
//   d      lane l: D[row=(l>>4)*4+r][col=l&15]
template <int KTOT, int NCOLS, bool AF32>
__global__ __launch_bounds__(256) void gemm_mfma_kernel(
    const void* __restrict__ Aptr, const ushort* __restrict__ Bt,
    const float* __restrict__ dinv, ushort* __restrict__ Cbf, int M) {
    constexpr int KP = 128;           // K panel in LDS
    constexpr int COLT = NCOLS / 16;  // 8 (gemm1) or 4 (gemm2)
    __shared__ ushort Bs[NCOLS][KP + 8];
    int tid = threadIdx.x;
    int wave = tid >> 6, lane = tid & 63;
    int quad = lane >> 4, l16 = lane & 15;
    int row0 = blockIdx.x * 64;
    int rowA = row0 + wave * 16 + l16;
    int rowAc = min(rowA, M - 1);

    floatx4 acc[COLT];
#pragma unroll
    for (int t = 0; t < COLT; t++) acc[t] = (floatx4){0.f, 0.f, 0.f, 0.f};

    for (int kp = 0; kp < KTOT; kp += KP) {
        for (int u = tid; u < NCOLS * (KP / 8); u += 256) {
            int n = u / (KP / 8);
            int k8 = (u % (KP / 8)) * 8;
            *(short8*)&Bs[n][k8] = *(const short8*)(Bt + (size_t)n * KTOT + kp + k8);
        }
        __syncthreads();
#pragma unroll
        for (int kc = 0; kc < KP / 32; kc++) {
            int kk = kp + kc * 32 + quad * 8;
            short8 a;
            if (AF32) {
                const float* ap = (const float*)Aptr + (size_t)rowAc * KTOT + kk;
#pragma unroll
                for (int j = 0; j < 8; j++) a[j] = (short)f32_to_bf16_bits(ap[j]);
            } else {
                a = *(const short8*)((const ushort*)Aptr + (size_t)rowAc * KTOT + kk);
            }
#pragma unroll
            for (int t = 0; t < COLT; t++) {
                short8 b = *(const short8*)&Bs[t * 16 + l16][kc * 32 + quad * 8];
                acc[t] = __builtin_amdgcn_mfma_f32_16x16x32_bf16(a, b, acc[t], 0, 0, 0);
            }
        }
        __syncthreads();
    }

#pragma unroll
    for (int r = 0; r < 4; r++) {
        int row = row0 + wave * 16 + quad * 4 + r;
        if (row < M) {
            float dv = dinv[row];
#pragma unroll
            for (int t = 0; t < COLT; t++)
                Cbf[(size_t)row * NCOLS + t * 16 + l16] = f32_to_bf16_bits(dv * acc[t][r]);
        }
    }
}

// ---------------- SpMM (bf16 gather, fp32 accumulate) ----------------------
// Xin rows are pre-scaled by dinv[col]; apply dinv[row] once at the end.
__global__ __launch_bounds__(256) void spmm_bf16_f128_kernel(
    const int* __restrict__ row_ptr, const int* __restrict__ cols,
    const float* __restrict__ dinv, const ushort* __restrict__ Xin,
    ushort* __restrict__ Yout, int n) {
    int wv = (int)((blockIdx.x * 256 + threadIdx.x) >> 6);
    int lane = threadIdx.x & 63;
    if (wv >= n) return;
    int beg = row_ptr[wv], end = row_ptr[wv + 1];
    float a0 = 0.f, a1 = 0.f;
    int e = beg;
    for (; e + 4 <= end; e += 4) {
        int c0 = cols[e], c1 = cols[e + 1], c2 = cols[e + 2], c3 = cols[e + 3];
        uint u0 = *(const uint*)(Xin + (size_t)c0 * 128 + lane * 2);
        uint u1 = *(const uint*)(Xin + (size_t)c1 * 128 + lane * 2);
        uint u2 = *(const uint*)(Xin + (size_t)c2 * 128 + lane * 2);
        uint u3 = *(const uint*)(Xin + (size_t)c3 * 128 + lane * 2);
        a0 += bf16lo_to_f32(u0); a1 += bf16hi_to_f32(u0);
        a0 += bf16lo_to_f32(u1); a1 += bf16hi_to_f32(u1);
        a0 += bf16lo_to_f32(u2); a1 += bf16hi_to_f32(u2);
        a0 += bf16lo_to_f32(u3); a1 += bf16hi_to_f32(u3);
    }
    for (; e < end; e++) {
        uint u = *(const uint*)(Xin + (size_t)cols[e] * 128 + lane * 2);
        a0 += bf16lo_to_f32(u);
        a1 += bf16hi_to_f32(u);
    }
    float dv = dinv[wv];
    a0 = fmaxf(dv * a0, 0.f);  // relu
    a1 = fmaxf(dv * a1, 0.f);
    uint out = (uint)f32_to_bf16_bits(a0) | ((uint)f32_to_bf16_bits(a1) << 16);
    *(uint*)(Yout + (size_t)wv * 128 + lane * 2) = out;
}

__global__ __launch_bounds__(256) void spmm_bf16_f64_kernel(
    const int* __restrict__ row_ptr, const int* __restrict__ cols,
    const float* __restrict__ dinv, const ushort* __restrict__ Xin,
    float* __restrict__ Yout, int n) {
    int wv = (int)((blockIdx.x * 256 + threadIdx.x) >> 6);
    int lane = threadIdx.x & 63;
    if (wv >= n) return;
    int beg = row_ptr[wv], end = row_ptr[wv + 1];
    float acc = 0.f;
    int e = beg;
    for (; e + 4 <= end; e += 4) {
        int c0 = cols[e], c1 = cols[e + 1], c2 = cols[e + 2], c3 = cols[e + 3];
        uint u0 = Xin[(size_t)c0 * 64 + lane];
        uint u1 = Xin[(size_t)c1 * 64 + lane];
        uint u2 = Xin[(size_t)c2 * 64 + lane];
        uint u3 = Xin[(size_t)c3 * 64 + lane];
        acc += bf16lo_to_f32(u0);
        acc += bf16lo_to_f32(u1);
        acc += bf16lo_to_f32(u2);
        acc += bf16lo_to_f32(u3);
    }
    for (; e < end; e++) {
        acc += bf16lo_to_f32((uint)Xin[(size_t)cols[e] * 64 + lane]);
    }
    Yout[(size_t)wv * 64 + lane] = dinv[wv] * acc;
}

// ---------------- launch ----------------------------------------------------

extern "C" void kernel_launch(void* const* d_in, const int* in_sizes, int n_in,
                              void* d_out, int out_size, void* d_ws, size_t ws_size,
                              hipStream_t stream) {
    const float* X  = (const float*)d_in[0];
    const float* W1 = (const float*)d_in[1];
    const float* W2 = (const float*)d_in[2];
    const int* erow = (const int*)d_in[3];
    const int* ecol = (const int*)d_in[4];

    const int N = in_sizes[0] / 256;  // 100000 (< 2^17 required for binP packing)
    const int E = in_sizes[3];        // 1700000
    const int G = (N + 1023) >> 10;   // row scan blocks (98 <= 256)

    const int nblk = (E + CSR_EPB - 1) / CSR_EPB;  // 208
    const int SL = 256 * nblk;                     // hist scan length
    const int GS = (SL + 1023) >> 10;              // 52 <= 256
    const int GMAX = (G > GS) ? G : GS;

    char* ws = (char*)d_ws;
    size_t off = 0;
    auto carve = [&](size_t bytes) -> char* {
        char* p = ws + off;
        off += (bytes + 255) & ~(size_t)255;
        return p;
    };
    int*    deg       = (int*)   carve((size_t)N * 4);
    float*  dinv      = (float*) carve((size_t)N * 4);
    int*    row_ptr   = (int*)   carve((size_t)(N + 1) * 4);
    int*    blk_total = (int*)   carve((size_t)GMAX * 4);
    int*    blk_off   = (int*)   carve((size_t)(GMAX + 1) * 4);
    int*    offG0     = (int*)   carve((size_t)(SL + 1) * 4);
    int*    offG1     = (int*)   carve((size_t)(SL + 1) * 4);
    // union region: e2 (E*8) + binP (E*4) dead before GEMM1 writes XW1.
    size_t e2_bytes   = ((size_t)E * 8 + 255) & ~(size_t)255;
    size_t uni_bytes  = e2_bytes + (size_t)E * 4;
    size_t xw1_bytes  = (size_t)N * 128 * 2;
    char*  uni        = carve(uni_bytes > xw1_bytes ? uni_bytes : xw1_bytes);
    int2*   e2        = (int2*)uni;
    int*    binP      = (int*)(uni + e2_bytes);
    ushort* XW1       = (ushort*)uni;
    int*    csr_col   = (int*)   carve((size_t)E * 4);
    ushort* W1t       = (ushort*)carve((size_t)256 * 128 * 2);  // [128][256]
    ushort* W2t       = (ushort*)carve((size_t)128 * 64 * 2);   // [64][128]
    ushort* H         = (ushort*)carve((size_t)N * 128 * 2);
    ushort* HW2       = (ushort*)carve((size_t)N * 64 * 2);

    // --- CSR build: col-sort then row-sort (R5) ---
    edge_hist_kernel<<<nblk, 256, 0, stream>>>(ecol, offG0, E, nblk);
    scan_phase1_kernel<<<GS, 256, 0, stream>>>(offG0, offG0, blk_total, SL);
    scan_phase2_kernel<<<1, 256, 0, stream>>>(blk_total, blk_off, GS);
    scan_phase3_kernel<<<(SL + 255) / 256, 256, 0, stream>>>(offG0, blk_off, SL, GS);
    col_bin_kernel<<<nblk, 256, 0, stream>>>(erow, ecol, offG0, e2, E, nblk);

    edge_hist2_kernel<<<nblk, 256, 0, stream>>>(e2, offG1, E, nblk);
    scan_phase1_kernel<<<GS, 256, 0, stream>>>(offG1, offG1, blk_total, SL);
    scan_phase2_kernel<<<1, 256, 0, stream>>>(blk_total, blk_off, GS);
    scan_phase3_kernel<<<(SL + 255) / 256, 256, 0, stream>>>(offG1, blk_off, SL, GS);
    row_bin_kernel<<<nblk, 256, 0, stream>>>(e2, offG1, binP, E, nblk);

    // degrees (no global atomics), dinv, row_ptr
    deg_from_bin_kernel<<<256, 256, 0, stream>>>(binP, offG1, deg, E, nblk, N);
    dinv_kernel<<<(N + 255) / 256, 256, 0, stream>>>(deg, dinv, N);
    scan_phase1_kernel<<<G, 256, 0, stream>>>(deg, row_ptr, blk_total, N);
    scan_phase2_kernel<<<1, 256, 0, stream>>>(blk_total, blk_off, G);
    scan_phase3_kernel<<<(N + 255) / 256, 256, 0, stream>>>(row_ptr, blk_off, N, G);

    edge_scatter_kernel<<<256, 256, 0, stream>>>(binP, offG1, row_ptr, csr_col, E, nblk, N);

    // weights: cast + transpose to bf16 [n][k]
    cast_transpose_kernel<<<(256 * 128 + 255) / 256, 256, 0, stream>>>(W1, W1t, 256, 128);
    cast_transpose_kernel<<<(128 * 64 + 255) / 256, 256, 0, stream>>>(W2, W2t, 128, 64);

    // GEMM1: XW1(bf16) = dinv .* (X @ W1)   (overwrites e2/binP region — dead)
    gemm_mfma_kernel<256, 128, true><<<(N + 63) / 64, 256, 0, stream>>>(
        (const void*)X, W1t, dinv, XW1, N);

    // SpMM1: H(bf16) = relu(dinv .* sum gather XW1)
    spmm_bf16_f128_kernel<<<(N + 3) / 4, 256, 0, stream>>>(row_ptr, csr_col, dinv, XW1, H, N);

    // GEMM2: HW2(bf16) = dinv .* (H @ W2)
    gemm_mfma_kernel<128, 64, false><<<(N + 63) / 64, 256, 0, stream>>>(
        (const void*)H, W2t, dinv, HW2, N);

    // SpMM2: out(fp32) = dinv .* sum gather HW2
    spmm_bf16_f64_kernel<<<(N + 3) / 4, 256, 0, stream>>>(row_ptr, csr_col, dinv, HW2, (float*)d_out, N);
}

// Round 7
// 374.057 us; speedup vs baseline: 1.4428x; 1.1783x over previous
//
#include <hip/hip_runtime.h>
#include <hip/hip_bf16.h>

// ---------------------------------------------------------------------------
// GCN forward: out = A_hat @ ( (relu(A_hat @ (X@W1))) @ W2 )
// A_hat = D^-1/2 (A) D^-1/2, edges given as (row, col) pairs incl. self loops.
//
// R2: internal tensors bf16, GEMMs on MFMA 16x16x32_bf16, SpMM gathers bf16.
// R3: csr_w eliminated (w separable) — GEMM epilogues pre-scale rows by dinv.
// R4: CSR build via 2-level counting sort (all atomics in LDS).
// R5: deg from binP histogram (no global atomics). Col-sort tried: FETCH
//     byte-identical -> locality hypothesis dead, sort removed in R6.
// R6: (a) SpMM restructured: 16 lanes/row, 4 rows/wave, dwordx4 gathers
//     (was 1 dword x 64 lanes/edge -> 4x fewer VMEM instrs, 4x less addr
//     VALU; kernel was issue-bound at 36% VALU / 36% HBM). (b) col-sort
//     passes dropped. (c) dinv fused into deg kernel, weight casts fused.
// ---------------------------------------------------------------------------

typedef __attribute__((ext_vector_type(8))) short short8;
typedef __attribute__((ext_vector_type(4))) float floatx4;

static __device__ __forceinline__ ushort f32_to_bf16_bits(float f) {
    union { ushort u; __hip_bfloat16 b; } cv;
    cv.b = __float2bfloat16(f);
    return cv.u;
}
static __device__ __forceinline__ float bf16lo_to_f32(uint u) {
    return __uint_as_float(u << 16);
}
static __device__ __forceinline__ float bf16hi_to_f32(uint u) {
    return __uint_as_float(u & 0xffff0000u);
}
static __device__ __forceinline__ uint pack2bf(float a, float b) {
    return (uint)f32_to_bf16_bits(a) | ((uint)f32_to_bf16_bits(b) << 16);
}

#define CSR_EPB 8192

// ---- generic 3-phase device-wide exclusive scan (1024 elems per block) ----
__global__ __launch_bounds__(256) void scan_phase1_kernel(
    const int* __restrict__ in, int* __restrict__ out,
    int* __restrict__ block_total, int n) {
    __shared__ int tsum[256];
    int t = threadIdx.x;
    int base = blockIdx.x * 1024 + t * 4;
    int v0 = (base + 0 < n) ? in[base + 0] : 0;
    int v1 = (base + 1 < n) ? in[base + 1] : 0;
    int v2 = (base + 2 < n) ? in[base + 2] : 0;
    int v3 = (base + 3 < n) ? in[base + 3] : 0;
    tsum[t] = v0 + v1 + v2 + v3;
    __syncthreads();
    for (int off = 1; off < 256; off <<= 1) {
        int x = (t >= off) ? tsum[t - off] : 0;
        __syncthreads();
        tsum[t] += x;
        __syncthreads();
    }
    if (t == 255) block_total[blockIdx.x] = tsum[255];
    int run = (t == 0) ? 0 : tsum[t - 1];
    if (base + 0 < n) out[base + 0] = run; run += v0;
    if (base + 1 < n) out[base + 1] = run; run += v1;
    if (base + 2 < n) out[base + 2] = run; run += v2;
    if (base + 3 < n) out[base + 3] = run;
}

__global__ __launch_bounds__(256) void scan_phase2_kernel(
    const int* __restrict__ block_total, int* __restrict__ block_offset, int G) {
    __shared__ int s[256];
    int t = threadIdx.x;
    s[t] = (t < G) ? block_total[t] : 0;
    __syncthreads();
    for (int off = 1; off < 256; off <<= 1) {
        int x = (t >= off) ? s[t - off] : 0;
        __syncthreads();
        s[t] += x;
        __syncthreads();
    }
    if (t < G) block_offset[t] = (t == 0) ? 0 : s[t - 1];
    if (t == 0) block_offset[G] = s[255];
}

__global__ __launch_bounds__(256) void scan_phase3_kernel(
    int* __restrict__ arr, const int* __restrict__ block_offset, int n, int G) {
    int i = blockIdx.x * blockDim.x + threadIdx.x;
    if (i < n) arr[i] += block_offset[i >> 10];
    if (i == 0) arr[n] = block_offset[G];
}

// ---- CSR build: row-bucket counting sort (bucket = row>>9) ----------------

__global__ __launch_bounds__(256) void edge_hist_kernel(
    const int* __restrict__ keys, int* __restrict__ histG, int E, int nblk) {
    __shared__ int h[256];
    int t = threadIdx.x;
    h[t] = 0;
    __syncthreads();
    int base = blockIdx.x * CSR_EPB;
    int end = min(base + CSR_EPB, E);
    for (int i = base + t; i < end; i += 256)
        atomicAdd(&h[keys[i] >> 9], 1);
    __syncthreads();
    histG[t * nblk + blockIdx.x] = h[t];
}

// bin edges by row bucket -> packed (row&511)<<17 | col  (N < 2^17).
__global__ __launch_bounds__(256) void edge_bin_kernel(
    const int* __restrict__ rows, const int* __restrict__ colsIn,
    const int* __restrict__ offG, int* __restrict__ binP, int E, int nblk) {
    __shared__ int cur[256];
    int t = threadIdx.x;
    cur[t] = offG[t * nblk + blockIdx.x];
    __syncthreads();
    int base = blockIdx.x * CSR_EPB;
    int end = min(base + CSR_EPB, E);
    for (int i = base + t; i < end; i += 256) {
        int r = rows[i], c = colsIn[i];
        int p = atomicAdd(&cur[r >> 9], 1);
        binP[p] = ((r & 511) << 17) | c;
    }
}

// per-row degrees + dinv via per-bucket LDS histogram (no global atomics).
__global__ __launch_bounds__(256) void deg_dinv_from_bin_kernel(
    const int* __restrict__ binP, const int* __restrict__ offG,
    int* __restrict__ deg, float* __restrict__ dinv, int E, int nblk, int N) {
    __shared__ int cnt[512];
    int b = blockIdx.x;
    int rbase = b << 9;
    if (rbase >= N) return;
    int t = threadIdx.x;
    for (int i = t; i < 512; i += 256) cnt[i] = 0;
    __syncthreads();
    int bs = offG[b * nblk];
    int be = (b + 1 < 256) ? offG[(b + 1) * nblk] : E;
    for (int e = bs + t; e < be; e += 256)
        atomicAdd(&cnt[binP[e] >> 17], 1);
    __syncthreads();
    for (int i = t; i < 512; i += 256) {
        int r = rbase + i;
        if (r < N) {
            int d = cnt[i];
            deg[r] = d;
            dinv[r] = 1.0f / sqrtf(fmaxf((float)d, 1e-24f));
        }
    }
}

// one block per row bucket; LDS row cursors; scatter confined to this
// bucket's csr_col window (L2-resident).
__global__ __launch_bounds__(256) void edge_scatter_kernel(
    const int* __restrict__ binP, const int* __restrict__ offG,
    const int* __restrict__ row_ptr, int* __restrict__ csr_col,
    int E, int nblk, int N) {
    __shared__ int cur[512];
    int b = blockIdx.x;
    int rbase = b << 9;
    if (rbase >= N) return;
    int t = threadIdx.x;
    for (int i = t; i < 512; i += 256) {
        int r = rbase + i;
        cur[i] = (r < N) ? row_ptr[r] : 0;
    }
    __syncthreads();
    int bs = offG[b * nblk];
    int be = (b + 1 < 256) ? offG[(b + 1) * nblk] : E;
    for (int e = bs + t; e < be; e += 256) {
        int pk = binP[e];
        int rl = pk >> 17;
        int c = pk & 0x1ffff;
        int p = atomicAdd(&cur[rl], 1);
        csr_col[p] = c;
    }
}

// ---------------- fused weight cast + transpose (W1 and W2) ----------------
// W1t [128][256] <- W1 [256][128];  W2t [64][128] <- W2 [128][64].
__global__ void cast_weights_kernel(const float* __restrict__ W1, const float* __restrict__ W2,
                                    ushort* __restrict__ W1t, ushort* __restrict__ W2t) {
    int i = blockIdx.x * blockDim.x + threadIdx.x;
    if (i < 256 * 128) {
        int n = i >> 8, k = i & 255;           // W1t[n][k], K=256
        W1t[i] = f32_to_bf16_bits(W1[k * 128 + n]);
    } else {
        int j = i - 256 * 128;
        if (j < 128 * 64) {
            int n = j >> 7, k = j & 127;       // W2t[n][k], K=128
            W2t[j] = f32_to_bf16_bits(W2[k * 64 + n]);
        }
    }
}

// ---------------- MFMA GEMM -----------------------------------------------
// C[M,NCOLS](bf16) = dinv[row] * (A[M,KTOT] @ Bt^T); Bt is [NCOLS][KTOT] bf16.
// MFMA layouts (HW-verified per guide m89/m120):
//   a_frag lane l: A[m=l&15][k=(l>>4)*8+j]
//   b_frag lane l: B[k=(l>>4)*8+j][n=l&15]
//   d      lane l: D[row=(l>>4)*4+r][col=l&15]
template <int KTOT, int NCOLS, bool AF32>
__global__ __launch_bounds__(256) void gemm_mfma_kernel(
    const void* __restrict__ Aptr, const ushort* __restrict__ Bt,
    const float* __restrict__ dinv, ushort* __restrict__ Cbf, int M) {
    constexpr int KP = 128;
    constexpr int COLT = NCOLS / 16;
    __shared__ ushort Bs[NCOLS][KP + 8];
    int tid = threadIdx.x;
    int wave = tid >> 6, lane = tid & 63;
    int quad = lane >> 4, l16 = lane & 15;
    int row0 = blockIdx.x * 64;
    int rowA = row0 + wave * 16 + l16;
    int rowAc = min(rowA, M - 1);

    floatx4 acc[COLT];
#pragma unroll
    for (int t = 0; t < COLT; t++) acc[t] = (floatx4){0.f, 0.f, 0.f, 0.f};

    for (int kp = 0; kp < KTOT; kp += KP) {
        for (int u = tid; u < NCOLS * (KP / 8); u += 256) {
            int n = u / (KP / 8);
            int k8 = (u % (KP / 8)) * 8;
            *(short8*)&Bs[n][k8] = *(const short8*)(Bt + (size_t)n * KTOT + kp + k8);
        }
        __syncthreads();
#pragma unroll
        for (int kc = 0; kc < KP / 32; kc++) {
            int kk = kp + kc * 32 + quad * 8;
            short8 a;
            if (AF32) {
                const float* ap = (const float*)Aptr + (size_t)rowAc * KTOT + kk;
#pragma unroll
                for (int j = 0; j < 8; j++) a[j] = (short)f32_to_bf16_bits(ap[j]);
            } else {
                a = *(const short8*)((const ushort*)Aptr + (size_t)rowAc * KTOT + kk);
            }
#pragma unroll
            for (int t = 0; t < COLT; t++) {
                short8 b = *(const short8*)&Bs[t * 16 + l16][kc * 32 + quad * 8];
                acc[t] = __builtin_amdgcn_mfma_f32_16x16x32_bf16(a, b, acc[t], 0, 0, 0);
            }
        }
        __syncthreads();
    }

#pragma unroll
    for (int r = 0; r < 4; r++) {
        int row = row0 + wave * 16 + quad * 4 + r;
        if (row < M) {
            float dv = dinv[row];
#pragma unroll
            for (int t = 0; t < COLT; t++)
                Cbf[(size_t)row * NCOLS + t * 16 + l16] = f32_to_bf16_bits(dv * acc[t][r]);
        }
    }
}

// ---------------- SpMM: 16 lanes/row, 4 rows/wave --------------------------
// Xin rows pre-scaled by dinv[col]; apply dinv[row] at the end.
// F=128: lane lg covers features lg*8..lg*8+7 (dwordx4 gather per edge).
__global__ __launch_bounds__(256) void spmm_f128_kernel(
    const int* __restrict__ row_ptr, const int* __restrict__ cols,
    const float* __restrict__ dinv, const ushort* __restrict__ Xin,
    ushort* __restrict__ Yout, int n) {
    int w = (int)((blockIdx.x * 256 + threadIdx.x) >> 6);
    int lane = threadIdx.x & 63;
    int g = lane >> 4, lg = lane & 15;
    int row = w * 4 + g;
    bool ok = row < n;
    int rc = ok ? row : (n - 1);
    int beg = row_ptr[rc];
    int end = ok ? row_ptr[rc + 1] : beg;
    float acc[8];
#pragma unroll
    for (int i = 0; i < 8; i++) acc[i] = 0.f;

    int e = beg;
    for (; e + 2 <= end; e += 2) {
        int c0 = cols[e], c1 = cols[e + 1];
        uint4 u0 = *(const uint4*)(Xin + (size_t)c0 * 128 + lg * 8);
        uint4 u1 = *(const uint4*)(Xin + (size_t)c1 * 128 + lg * 8);
        acc[0] += bf16lo_to_f32(u0.x); acc[1] += bf16hi_to_f32(u0.x);
        acc[2] += bf16lo_to_f32(u0.y); acc[3] += bf16hi_to_f32(u0.y);
        acc[4] += bf16lo_to_f32(u0.z); acc[5] += bf16hi_to_f32(u0.z);
        acc[6] += bf16lo_to_f32(u0.w); acc[7] += bf16hi_to_f32(u0.w);
        acc[0] += bf16lo_to_f32(u1.x); acc[1] += bf16hi_to_f32(u1.x);
        acc[2] += bf16lo_to_f32(u1.y); acc[3] += bf16hi_to_f32(u1.y);
        acc[4] += bf16lo_to_f32(u1.z); acc[5] += bf16hi_to_f32(u1.z);
        acc[6] += bf16lo_to_f32(u1.w); acc[7] += bf16hi_to_f32(u1.w);
    }
    if (e < end) {
        int c = cols[e];
        uint4 u = *(const uint4*)(Xin + (size_t)c * 128 + lg * 8);
        acc[0] += bf16lo_to_f32(u.x); acc[1] += bf16hi_to_f32(u.x);
        acc[2] += bf16lo_to_f32(u.y); acc[3] += bf16hi_to_f32(u.y);
        acc[4] += bf16lo_to_f32(u.z); acc[5] += bf16hi_to_f32(u.z);
        acc[6] += bf16lo_to_f32(u.w); acc[7] += bf16hi_to_f32(u.w);
    }
    if (ok) {
        float dv = dinv[row];
#pragma unroll
        for (int i = 0; i < 8; i++) acc[i] = fmaxf(dv * acc[i], 0.f);  // relu
        uint4 o;
        o.x = pack2bf(acc[0], acc[1]);
        o.y = pack2bf(acc[2], acc[3]);
        o.z = pack2bf(acc[4], acc[5]);
        o.w = pack2bf(acc[6], acc[7]);
        *(uint4*)(Yout + (size_t)row * 128 + lg * 8) = o;
    }
}

// F=64: lane lg covers features lg*4..lg*4+3 (dwordx2 gather), fp32 out.
__global__ __launch_bounds__(256) void spmm_f64_kernel(
    const int* __restrict__ row_ptr, const int* __restrict__ cols,
    const float* __restrict__ dinv, const ushort* __restrict__ Xin,
    float* __restrict__ Yout, int n) {
    int w = (int)((blockIdx.x * 256 + threadIdx.x) >> 6);
    int lane = threadIdx.x & 63;
    int g = lane >> 4, lg = lane & 15;
    int row = w * 4 + g;
    bool ok = row < n;
    int rc = ok ? row : (n - 1);
    int beg = row_ptr[rc];
    int end = ok ? row_ptr[rc + 1] : beg;
    float acc[4];
#pragma unroll
    for (int i = 0; i < 4; i++) acc[i] = 0.f;

    int e = beg;
    for (; e + 2 <= end; e += 2) {
        int c0 = cols[e], c1 = cols[e + 1];
        uint2 u0 = *(const uint2*)(Xin + (size_t)c0 * 64 + lg * 4);
        uint2 u1 = *(const uint2*)(Xin + (size_t)c1 * 64 + lg * 4);
        acc[0] += bf16lo_to_f32(u0.x); acc[1] += bf16hi_to_f32(u0.x);
        acc[2] += bf16lo_to_f32(u0.y); acc[3] += bf16hi_to_f32(u0.y);
        acc[0] += bf16lo_to_f32(u1.x); acc[1] += bf16hi_to_f32(u1.x);
        acc[2] += bf16lo_to_f32(u1.y); acc[3] += bf16hi_to_f32(u1.y);
    }
    if (e < end) {
        int c = cols[e];
        uint2 u = *(const uint2*)(Xin + (size_t)c * 64 + lg * 4);
        acc[0] += bf16lo_to_f32(u.x); acc[1] += bf16hi_to_f32(u.x);
        acc[2] += bf16lo_to_f32(u.y); acc[3] += bf16hi_to_f32(u.y);
    }
    if (ok) {
        float dv = dinv[row];
        float4 o = make_float4(dv * acc[0], dv * acc[1], dv * acc[2], dv * acc[3]);
        *(float4*)(Yout + (size_t)row * 64 + lg * 4) = o;
    }
}

// ---------------- launch ----------------------------------------------------

extern "C" void kernel_launch(void* const* d_in, const int* in_sizes, int n_in,
                              void* d_out, int out_size, void* d_ws, size_t ws_size,
                              hipStream_t stream) {
    const float* X  = (const float*)d_in[0];
    const float* W1 = (const float*)d_in[1];
    const float* W2 = (const float*)d_in[2];
    const int* erow = (const int*)d_in[3];
    const int* ecol = (const int*)d_in[4];

    const int N = in_sizes[0] / 256;  // 100000 (< 2^17 for binP packing)
    const int E = in_sizes[3];        // 1700000
    const int G = (N + 1023) >> 10;   // row scan blocks (98 <= 256)

    const int nblk = (E + CSR_EPB - 1) / CSR_EPB;  // 208
    const int SL = 256 * nblk;                     // hist scan length
    const int GS = (SL + 1023) >> 10;              // 52 <= 256
    const int GMAX = (G > GS) ? G : GS;

    char* ws = (char*)d_ws;
    size_t off = 0;
    auto carve = [&](size_t bytes) -> char* {
        char* p = ws + off;
        off += (bytes + 255) & ~(size_t)255;
        return p;
    };
    int*    deg       = (int*)   carve((size_t)N * 4);
    float*  dinv      = (float*) carve((size_t)N * 4);
    int*    row_ptr   = (int*)   carve((size_t)(N + 1) * 4);
    int*    blk_total = (int*)   carve((size_t)GMAX * 4);
    int*    blk_off   = (int*)   carve((size_t)(GMAX + 1) * 4);
    int*    offG      = (int*)   carve((size_t)(SL + 1) * 4);
    // union: binP (E*4) dead before GEMM1 writes XW1 (N*128*2).
    size_t binP_bytes = (size_t)E * 4;
    size_t xw1_bytes  = (size_t)N * 128 * 2;
    char*  uni        = carve(binP_bytes > xw1_bytes ? binP_bytes : xw1_bytes);
    int*    binP      = (int*)uni;
    ushort* XW1       = (ushort*)uni;
    int*    csr_col   = (int*)   carve((size_t)E * 4);
    ushort* W1t       = (ushort*)carve((size_t)256 * 128 * 2);  // [128][256]
    ushort* W2t       = (ushort*)carve((size_t)128 * 64 * 2);   // [64][128]
    ushort* H         = (ushort*)carve((size_t)N * 128 * 2);
    ushort* HW2       = (ushort*)carve((size_t)N * 64 * 2);

    // --- CSR build: row-bucket counting sort ---
    edge_hist_kernel<<<nblk, 256, 0, stream>>>(erow, offG, E, nblk);
    scan_phase1_kernel<<<GS, 256, 0, stream>>>(offG, offG, blk_total, SL);
    scan_phase2_kernel<<<1, 256, 0, stream>>>(blk_total, blk_off, GS);
    scan_phase3_kernel<<<(SL + 255) / 256, 256, 0, stream>>>(offG, blk_off, SL, GS);
    edge_bin_kernel<<<nblk, 256, 0, stream>>>(erow, ecol, offG, binP, E, nblk);

    deg_dinv_from_bin_kernel<<<256, 256, 0, stream>>>(binP, offG, deg, dinv, E, nblk, N);
    scan_phase1_kernel<<<G, 256, 0, stream>>>(deg, row_ptr, blk_total, N);
    scan_phase2_kernel<<<1, 256, 0, stream>>>(blk_total, blk_off, G);
    scan_phase3_kernel<<<(N + 255) / 256, 256, 0, stream>>>(row_ptr, blk_off, N, G);

    edge_scatter_kernel<<<256, 256, 0, stream>>>(binP, offG, row_ptr, csr_col, E, nblk, N);

    // weights: cast + transpose to bf16 [n][k] (fused W1+W2)
    cast_weights_kernel<<<(256 * 128 + 128 * 64 + 255) / 256, 256, 0, stream>>>(W1, W2, W1t, W2t);

    // GEMM1: XW1(bf16) = dinv .* (X @ W1)   (overwrites binP — dead)
    gemm_mfma_kernel<256, 128, true><<<(N + 63) / 64, 256, 0, stream>>>(
        (const void*)X, W1t, dinv, XW1, N);

    // SpMM1: H(bf16) = relu(dinv .* sum gather XW1)
    spmm_f128_kernel<<<(N + 15) / 16, 256, 0, stream>>>(row_ptr, csr_col, dinv, XW1, H, N);

    // GEMM2: HW2(bf16) = dinv .* (H @ W2)
    gemm_mfma_kernel<128, 64, false><<<(N + 63) / 64, 256, 0, stream>>>(
        (const void*)H, W2t, dinv, HW2, N);

    // SpMM2: out(fp32) = dinv .* sum gather HW2
    spmm_f64_kernel<<<(N + 15) / 16, 256, 0, stream>>>(row_ptr, csr_col, dinv, HW2, (float*)d_out, N);
}